// Round 11
// baseline (487.017 us; speedup 1.0000x reference)
//
#include <hip/hip_runtime.h>
#include <cstdint>
#include <cstddef>

typedef unsigned short u16;
using bf16x8 = __attribute__((ext_vector_type(8))) short;
using f32x4  = __attribute__((ext_vector_type(4))) float;

#define MFMA16(a, b, c) __builtin_amdgcn_mfma_f32_16x16x32_bf16((a), (b), (c), 0, 0, 0)

__device__ __forceinline__ u16 f2bf(float f) {
  union { float f; unsigned u; } x; x.f = f;
  unsigned r = x.u + 0x7fffu + ((x.u >> 16) & 1u);
  return (u16)(r >> 16);
}
__device__ __forceinline__ float bf2f(u16 h) {
  union { unsigned u; float f; } x; x.u = ((unsigned)h) << 16;
  return x.f;
}
__device__ __forceinline__ void gll16(const void* g, void* l) {
  __builtin_amdgcn_global_load_lds((const __attribute__((address_space(1))) void*)g,
                                   (__attribute__((address_space(3))) void*)l, 16, 0, 0);
}

union U8 { bf16x8 v; u16 u[8]; };

// ---------------- fused fp32 -> bf16 cast for all three tensors ----------------
// One dispatch instead of three (launch overhead ~10-15us each).
__global__ __launch_bounds__(256) void cvt3_kernel(const float* __restrict__ a,
                                                   const float* __restrict__ b,
                                                   const float* __restrict__ c,
                                                   u16* __restrict__ oa,
                                                   u16* __restrict__ ob,
                                                   u16* __restrict__ oc,
                                                   int n1, int n2, int n3) {
  int i = blockIdx.x * blockDim.x + threadIdx.x;
  const float* src; u16* dst; int j;
  if (i < n1)            { src = a; dst = oa; j = i; }
  else if (i < n1 + n2)  { src = b; dst = ob; j = i - n1; }
  else if (i < n1 + n2 + n3) { src = c; dst = oc; j = i - n1 - n2; }
  else return;
  float4 v = ((const float4*)src)[j];
  ushort4 o;
  o.x = f2bf(v.x); o.y = f2bf(v.y); o.z = f2bf(v.z); o.w = f2bf(v.w);
  ((ushort4*)dst)[j] = o;
}

// ---------------- 256x256 NT GEMM — m201-style 8-phase schedule ----
__global__ __launch_bounds__(512, 2) void gemm_bt256(const u16* __restrict__ A,
                                                     const u16* __restrict__ Bw,
                                                     const float* __restrict__ bias,
                                                     void* __restrict__ Cout,
                                                     int M, int N, int K, int out_bf16) {
  __shared__ u16 As_[2][16384];
  __shared__ u16 Bs_[2][16384];
  const int tid = threadIdx.x;
  const int lane = tid & 63, wave = tid >> 6;
  const int col = lane & 15, quad = lane >> 4;
  const int wr = wave >> 2, wc = wave & 3;
  const int bm = blockIdx.y, bn = blockIdx.x;
  const u16* Ag = A + (size_t)bm * 256 * K;
  const u16* Bg = Bw + (size_t)bn * 256 * K;
  const int srow = tid >> 2;                       // 0..127
  const int sslot = tid & 3;
  const int ssw = (sslot ^ ((srow >> 1) & 3)) << 3;
  const size_t g0 = (size_t)srow * K + ssw;
  const size_t g1 = (size_t)(srow + 128) * K + ssw;
  const int swq = (quad ^ ((col >> 1) & 3)) << 3;
  const int aro = (wr * 128 + col) * 32 + swq;
  const int bro = (wc * 64 + col) * 32 + swq;
  u16* const As0 = &As_[0][0]; u16* const As1 = &As_[1][0];
  u16* const Bs0 = &Bs_[0][0]; u16* const Bs1 = &Bs_[1][0];
  f32x4 acc[8][4] = {};
  bf16x8 a[8], bq[2];
  const int NI = K >> 7;  // iterations of 2 K-tiles

#define STG_A(BUF, KS, KT) do { \
    gll16(Ag + g0 + (KT) + (KS) * 32, (void*)((BUF) + (KS) * 8192 + tid * 8)); \
    gll16(Ag + g1 + (KT) + (KS) * 32, (void*)((BUF) + (KS) * 8192 + 4096 + tid * 8)); } while (0)
#define STG_B(BUF, KS, KT) do { \
    gll16(Bg + g0 + (KT) + (KS) * 32, (void*)((BUF) + (KS) * 8192 + tid * 8)); \
    gll16(Bg + g1 + (KT) + (KS) * 32, (void*)((BUF) + (KS) * 8192 + 4096 + tid * 8)); } while (0)
#define RD_A(BUF, KS) do { _Pragma("unroll") \
    for (int m_ = 0; m_ < 8; m_++) \
      a[m_] = *(const bf16x8*)&(BUF)[(KS) * 8192 + aro + m_ * 512]; } while (0)
#define RD_B(BUF, KS, NH) do { _Pragma("unroll") \
    for (int n_ = 0; n_ < 2; n_++) \
      bq[n_] = *(const bf16x8*)&(BUF)[(KS) * 8192 + bro + ((NH) * 2 + n_) * 512]; } while (0)
#define MM(NH) do { _Pragma("unroll") \
    for (int m_ = 0; m_ < 8; m_++) { _Pragma("unroll") \
      for (int n_ = 0; n_ < 2; n_++) \
        acc[m_][(NH) * 2 + n_] = MFMA16(a[m_], bq[n_], acc[m_][(NH) * 2 + n_]); } } while (0)
#define PH(RDS, STGS, MMS, WT) do { \
    RDS; STGS; \
    __builtin_amdgcn_s_barrier(); \
    asm volatile("s_waitcnt lgkmcnt(0)" ::: "memory"); \
    __builtin_amdgcn_s_setprio(1); \
    MMS; \
    __builtin_amdgcn_s_setprio(0); \
    WT; \
    __builtin_amdgcn_s_barrier(); } while (0)
#define VM6 do { asm volatile("s_waitcnt vmcnt(6)" ::: "memory"); } while (0)
#define VM0 do { asm volatile("s_waitcnt vmcnt(0)" ::: "memory"); } while (0)
#define NOPW do { } while (0)

#define ITER(I, LAST) do { \
    const int kt1_ = ((2 * (I) + 1) << 6), kt2_ = kt1_ + 64, kt3_ = kt2_ + 64; \
    PH({ RD_A(As0, 0); RD_B(Bs0, 0, 0); }, { STG_B(Bs1, 1, kt1_); },                MM(0), NOPW); \
    PH({ RD_B(Bs0, 0, 1); },               { if (!(LAST)) STG_A(As0, 0, kt2_); },   MM(1), NOPW); \
    PH({ RD_A(As0, 1); RD_B(Bs0, 1, 1); }, { if (!(LAST)) STG_B(Bs0, 0, kt2_); },   MM(1), NOPW); \
    PH({ RD_B(Bs0, 1, 0); },               { if (!(LAST)) STG_A(As0, 1, kt2_); },   MM(0), \
       if (LAST) { VM0; } else { VM6; }); \
    PH({ RD_A(As1, 0); RD_B(Bs1, 0, 0); }, { if (!(LAST)) STG_B(Bs0, 1, kt2_); },   MM(0), NOPW); \
    PH({ RD_B(Bs1, 0, 1); },               { if (!(LAST)) STG_A(As1, 0, kt3_); },   MM(1), NOPW); \
    PH({ RD_A(As1, 1); RD_B(Bs1, 1, 1); }, { if (!(LAST)) STG_B(Bs1, 0, kt3_); },   MM(1), NOPW); \
    PH({ RD_B(Bs1, 1, 0); },               { if (!(LAST)) STG_A(As1, 1, kt3_); },   MM(0), \
       if (!(LAST)) { VM6; }); \
  } while (0)

  // prologue: tile0 all 4 halves + tile1 first 3 (14 gll); confirm tile0.
  STG_A(As0, 0, 0);  STG_B(Bs0, 0, 0);  STG_A(As0, 1, 0);  STG_B(Bs0, 1, 0);
  STG_A(As1, 0, 64); STG_B(Bs1, 0, 64); STG_A(As1, 1, 64);
  VM6;
  __builtin_amdgcn_s_barrier();

  for (int i = 0; i < NI - 1; ++i) ITER(i, false);
  ITER(NI - 1, true);

  // epilogue
#pragma unroll
  for (int i = 0; i < 8; i++) {
    const int row0 = bm * 256 + wr * 128 + i * 16 + quad * 4;
#pragma unroll
    for (int j = 0; j < 4; j++) {
      const int cn = bn * 256 + wc * 64 + j * 16 + col;
      const float bv = bias[cn];
#pragma unroll
      for (int r = 0; r < 4; r++) {
        float v = acc[i][j][r] + bv;
        size_t off = (size_t)(row0 + r) * N + cn;
        if (out_bf16) ((u16*)Cout)[off] = f2bf(v);
        else          ((float*)Cout)[off] = v;
      }
    }
  }
#undef STG_A
#undef STG_B
#undef RD_A
#undef RD_B
#undef MM
#undef PH
#undef VM6
#undef VM0
#undef NOPW
#undef ITER
}

// ---------------- 128x256 NT GEMM — 8-phase schedule, BM=128 ----------------
// Out-projection: grid (8,32) = 256 blocks = exactly 1/CU.
__global__ __launch_bounds__(512, 2) void gemm_bt128(const u16* __restrict__ A,
                                                     const u16* __restrict__ Bw,
                                                     const float* __restrict__ bias,
                                                     void* __restrict__ Cout,
                                                     int M, int N, int K, int out_bf16) {
  __shared__ u16 As_[2][8192];
  __shared__ u16 Bs_[2][16384];
  const int tid = threadIdx.x;
  const int lane = tid & 63, wave = tid >> 6;
  const int col = lane & 15, quad = lane >> 4;
  const int wr = wave >> 2, wc = wave & 3;
  const int bm = blockIdx.y, bn = blockIdx.x;
  const u16* Ag = A + (size_t)bm * 128 * K;
  const u16* Bg = Bw + (size_t)bn * 256 * K;
  const int srow = tid >> 2;                       // 0..127
  const int sslot = tid & 3;
  const int ssw = (sslot ^ ((srow >> 1) & 3)) << 3;
  const size_t g0 = (size_t)srow * K + ssw;
  const size_t g1 = (size_t)(srow + 128) * K + ssw;   // B only
  const int swq = (quad ^ ((col >> 1) & 3)) << 3;
  const int aro = (wr * 64 + col) * 32 + swq;          // per-wave M = 64
  const int bro = (wc * 64 + col) * 32 + swq;
  u16* const As0 = &As_[0][0]; u16* const As1 = &As_[1][0];
  u16* const Bs0 = &Bs_[0][0]; u16* const Bs1 = &Bs_[1][0];
  f32x4 acc[4][4] = {};
  bf16x8 a[4], bq[2];
  const int NI = K >> 7;  // iterations of 2 K-tiles

#define STG_A(BUF, KS, KT) do { \
    gll16(Ag + g0 + (KT) + (KS) * 32, (void*)((BUF) + (KS) * 4096 + tid * 8)); } while (0)
#define STG_B(BUF, KS, KT) do { \
    gll16(Bg + g0 + (KT) + (KS) * 32, (void*)((BUF) + (KS) * 8192 + tid * 8)); \
    gll16(Bg + g1 + (KT) + (KS) * 32, (void*)((BUF) + (KS) * 8192 + 4096 + tid * 8)); } while (0)
#define RD_A(BUF, KS) do { _Pragma("unroll") \
    for (int m_ = 0; m_ < 4; m_++) \
      a[m_] = *(const bf16x8*)&(BUF)[(KS) * 4096 + aro + m_ * 512]; } while (0)
#define RD_B(BUF, KS, NH) do { _Pragma("unroll") \
    for (int n_ = 0; n_ < 2; n_++) \
      bq[n_] = *(const bf16x8*)&(BUF)[(KS) * 8192 + bro + ((NH) * 2 + n_) * 512]; } while (0)
#define MM(NH) do { _Pragma("unroll") \
    for (int m_ = 0; m_ < 4; m_++) { _Pragma("unroll") \
      for (int n_ = 0; n_ < 2; n_++) \
        acc[m_][(NH) * 2 + n_] = MFMA16(a[m_], bq[n_], acc[m_][(NH) * 2 + n_]); } } while (0)
#define PH(RDS, STGS, MMS, WT) do { \
    RDS; STGS; \
    __builtin_amdgcn_s_barrier(); \
    asm volatile("s_waitcnt lgkmcnt(0)" ::: "memory"); \
    __builtin_amdgcn_s_setprio(1); \
    MMS; \
    __builtin_amdgcn_s_setprio(0); \
    WT; \
    __builtin_amdgcn_s_barrier(); } while (0)
#define VM4 do { asm volatile("s_waitcnt vmcnt(4)" ::: "memory"); } while (0)
#define VM0 do { asm volatile("s_waitcnt vmcnt(0)" ::: "memory"); } while (0)
#define NOPW do { } while (0)

#define ITER(I, LAST) do { \
    const int kt1_ = ((2 * (I) + 1) << 6), kt2_ = kt1_ + 64, kt3_ = kt2_ + 64; \
    PH({ RD_A(As0, 0); RD_B(Bs0, 0, 0); }, { STG_B(Bs1, 1, kt1_); },                MM(0), NOPW); \
    PH({ RD_B(Bs0, 0, 1); },               { if (!(LAST)) STG_A(As0, 0, kt2_); },   MM(1), NOPW); \
    PH({ RD_A(As0, 1); RD_B(Bs0, 1, 1); }, { if (!(LAST)) STG_B(Bs0, 0, kt2_); },   MM(1), NOPW); \
    PH({ RD_B(Bs0, 1, 0); },               { if (!(LAST)) STG_A(As0, 1, kt2_); },   MM(0), \
       if (LAST) { VM0; } else { VM4; }); \
    PH({ RD_A(As1, 0); RD_B(Bs1, 0, 0); }, { if (!(LAST)) STG_B(Bs0, 1, kt2_); },   MM(0), NOPW); \
    PH({ RD_B(Bs1, 0, 1); },               { if (!(LAST)) STG_A(As1, 0, kt3_); },   MM(1), NOPW); \
    PH({ RD_A(As1, 1); RD_B(Bs1, 1, 1); }, { if (!(LAST)) STG_B(Bs1, 0, kt3_); },   MM(1), NOPW); \
    PH({ RD_B(Bs1, 1, 0); },               { if (!(LAST)) STG_A(As1, 1, kt3_); },   MM(0), \
       if (!(LAST)) { VM4; }); \
  } while (0)

  // prologue: tile0 all 4 halves (6 gll) + tile1 A0,B0,A1 (4 gll); confirm tile0.
  STG_A(As0, 0, 0);  STG_B(Bs0, 0, 0);  STG_A(As0, 1, 0);  STG_B(Bs0, 1, 0);
  STG_A(As1, 0, 64); STG_B(Bs1, 0, 64); STG_A(As1, 1, 64);
  VM4;
  __builtin_amdgcn_s_barrier();

  for (int i = 0; i < NI - 1; ++i) ITER(i, false);
  ITER(NI - 1, true);

  // epilogue
#pragma unroll
  for (int i = 0; i < 4; i++) {
    const int row0 = bm * 128 + wr * 64 + i * 16 + quad * 4;
#pragma unroll
    for (int j = 0; j < 4; j++) {
      const int cn = bn * 256 + wc * 64 + j * 16 + col;
      const float bv = bias[cn];
#pragma unroll
      for (int r = 0; r < 4; r++) {
        float v = acc[i][j][r] + bv;
        size_t off = (size_t)(row0 + r) * N + cn;
        if (out_bf16) ((u16*)Cout)[off] = f2bf(v);
        else          ((float*)Cout)[off] = v;
      }
    }
  }
#undef STG_A
#undef STG_B
#undef RD_A
#undef RD_B
#undef MM
#undef PH
#undef VM4
#undef VM0
#undef NOPW
#undef ITER
}

// ---------------- RoPE + reorder + V transpose ----------------
__global__ __launch_bounds__(256) void rope_kernel(const u16* __restrict__ qkv,
                                                   const float* __restrict__ cosT,
                                                   const float* __restrict__ sinT,
                                                   u16* __restrict__ qo,
                                                   u16* __restrict__ ko,
                                                   u16* __restrict__ vt) {
  __shared__ u16 vs[128 * 72];
  const int bh = blockIdx.x;
  const int b = bh >> 4, h = bh & 15;
  const int tb = blockIdx.y;
  const int tid = threadIdx.x;
  const int tl = tid >> 2;        // 0..63
  const int g = tid & 3;
  const int t = tb * 64 + tl;
  const size_t qrow = ((size_t)(b * 2048 + t)) * 6144 + h * 128;
  const size_t orow = ((size_t)bh * 2048 + t) * 128;
  const int tt = t * 128;
  const int dl = g * 16, dh = 64 + dl;
  const float scale = 0.08838834764831845f;  // 1/sqrt(128)
#pragma unroll
  for (int cch = 0; cch < 2; cch++) {
    const int o8 = cch * 8;
    U8 ql, qh, kl, kh, vl, vh;
    ql.v = *(const bf16x8*)&qkv[qrow + dl + o8];
    qh.v = *(const bf16x8*)&qkv[qrow + dh + o8];
    kl.v = *(const bf16x8*)&qkv[qrow + 2048 + dl + o8];
    kh.v = *(const bf16x8*)&qkv[qrow + 2048 + dh + o8];
    vl.v = *(const bf16x8*)&qkv[qrow + 4096 + dl + o8];
    vh.v = *(const bf16x8*)&qkv[qrow + 4096 + dh + o8];
    float cl[8], ch_[8], sl[8], sh_[8];
    *(float4*)&cl[0]  = *(const float4*)&cosT[tt + dl + o8];
    *(float4*)&cl[4]  = *(const float4*)&cosT[tt + dl + o8 + 4];
    *(float4*)&ch_[0] = *(const float4*)&cosT[tt + dh + o8];
    *(float4*)&ch_[4] = *(const float4*)&cosT[tt + dh + o8 + 4];
    *(float4*)&sl[0]  = *(const float4*)&sinT[tt + dl + o8];
    *(float4*)&sl[4]  = *(const float4*)&sinT[tt + dl + o8 + 4];
    *(float4*)&sh_[0] = *(const float4*)&sinT[tt + dh + o8];
    *(float4*)&sh_[4] = *(const float4*)&sinT[tt + dh + o8 + 4];
    U8 aq, bq, ak, bk;
#pragma unroll
    for (int i = 0; i < 8; i++) {
      float qlf = bf2f(ql.u[i]), qhf = bf2f(qh.u[i]);
      float klf = bf2f(kl.u[i]), khf = bf2f(kh.u[i]);
      aq.u[i] = f2bf((qlf * cl[i]  - qhf * sl[i])  * scale);
      bq.u[i] = f2bf((qhf * ch_[i] + qlf * sh_[i]) * scale);
      ak.u[i] = f2bf(klf * cl[i]  - khf * sl[i]);
      bk.u[i] = f2bf(khf * ch_[i] + klf * sh_[i]);
    }
    *(bf16x8*)&qo[orow + dl + o8] = aq.v;
    *(bf16x8*)&qo[orow + dh + o8] = bq.v;
    *(bf16x8*)&ko[orow + dl + o8] = ak.v;
    *(bf16x8*)&ko[orow + dh + o8] = bk.v;
#pragma unroll
    for (int i = 0; i < 8; i++) {
      vs[(dl + o8 + i) * 72 + tl] = vl.u[i];
      vs[(dh + o8 + i) * 72 + tl] = vh.u[i];
    }
  }
  __syncthreads();
#pragma unroll
  for (int c = 0; c < 4; c++) {
    int idx = c * 256 + tid;
    int dd = idx >> 3, chk = idx & 7;
    bf16x8 vv = *(const bf16x8*)&vs[dd * 72 + chk * 8];
    *(bf16x8*)&vt[((size_t)bh * 128 + dd) * 2048 + tb * 64 + chk * 8] = vv;
  }
}

// ---------------- causal flash attention (no-max softmax) ----------------
// r7 balance map + XOR-swizzled LDS (K/V: r5-verified; P: r6-verified) +
// merged PV so each V fragment is read from LDS ONCE (shared by both
// q-subtiles; was read twice = 16 of 56 reads/wave/tile). Dual P buffers
// keep both q-subtiles' P live for the merged loop.
__global__ __launch_bounds__(256) void attn_kernel(const u16* __restrict__ Q,
                                                   const u16* __restrict__ Kk,
                                                   const u16* __restrict__ Vt,
                                                   u16* __restrict__ O) {
  __shared__ u16 Ks[64 * 128];       // 64 keys x 128 dims, XOR-swizzled rows
  __shared__ u16 Vs[128 * 64];       // 128 dims x 64 keys, XOR-swizzled rows
  __shared__ u16 Ps[4][2048];        // per-wave: 2 x (16 q x 64 keys), swizzled
  const int L = blockIdx.x;          // 0..511
  const int bh = (L < 256) ? (L >> 4) : 16 + ((L - 256) >> 4);
  const int qtile = (L < 256) ? (15 - (L & 15)) : (L & 15);
  const int b = bh >> 4, h = bh & 15;
  const int qb = qtile * 128;
  const int tid = threadIdx.x, wave = tid >> 6, lane = tid & 63;
  const int col = lane & 15, quad = lane >> 4;
  const int qw0 = qb + wave * 32;    // wave owns rows [qw0, qw0+31]
  const int qw1 = qw0 + 16;
  const u16* Qg = Q + (size_t)bh * 2048 * 128;
  const u16* Kg = Kk + (size_t)bh * 2048 * 128;
  const u16* Vg = Vt + (size_t)bh * 128 * 2048;
  bf16x8 qf0[4], qf1[4];
#pragma unroll
  for (int c = 0; c < 4; c++) {
    qf0[c] = *(const bf16x8*)&Qg[(size_t)(qw0 + col) * 128 + c * 32 + quad * 8];
    qf1[c] = *(const bf16x8*)&Qg[(size_t)(qw1 + col) * 128 + c * 32 + quad * 8];
  }
  f32x4 o0[8] = {}, o1[8] = {};
  float ls0[4] = {0.f, 0.f, 0.f, 0.f}, ls1[4] = {0.f, 0.f, 0.f, 0.f};
  const int ntiles = (qb + 128) >> 6;
  const int skr = tid >> 4, sks = tid & 15;   // K staging: 16 thr/row
  const int svr = tid >> 1, svc = tid & 1;    // V staging: 2 thr/row
  for (int it = 0; it < ntiles; ++it) {
    const int kt = it << 6;
    __syncthreads();
#pragma unroll
    for (int u = 0; u < 4; u++) {
      const int row = u * 16 + skr;
      *(bf16x8*)&Ks[row * 128 + ((sks ^ (row & 7)) << 3)] =
          *(const bf16x8*)&Kg[(size_t)(kt + row) * 128 + (sks << 3)];
    }
#pragma unroll
    for (int u = 0; u < 4; u++) {
      const int ch = svc + 2 * u;
      *(bf16x8*)&Vs[svr * 64 + ((ch ^ (svr & 7)) << 3)] =
          *(const bf16x8*)&Vg[(size_t)svr * 2048 + kt + (ch << 3)];
    }
    __syncthreads();
    if (kt > qw1 + 15) continue;     // wave-uniform; barriers stay matched
    const bool do0 = (kt <= qw0 + 15);
    f32x4 s0[4] = {}, s1[4] = {};
#pragma unroll
    for (int c = 0; c < 4; c++) {
#pragma unroll
      for (int kg = 0; kg < 4; kg++) {
        const int krow = kg * 16 + col;
        bf16x8 kf = *(const bf16x8*)&Ks[krow * 128 + (((c * 4 + quad) ^ (krow & 7)) << 3)];
        s0[kg] = MFMA16(qf0[c], kf, s0[kg]);
        s1[kg] = MFMA16(qf1[c], kf, s1[kg]);
      }
    }
    u16* pw0 = &Ps[wave][0];
    u16* pw1 = &Ps[wave][1024];
    if (do0) {
#pragma unroll
      for (int kg = 0; kg < 4; kg++)
#pragma unroll
        for (int r = 0; r < 4; r++) {
          int key = kt + kg * 16 + col, qg = qw0 + quad * 4 + r;
          float p = (key <= qg) ? __expf(s0[kg][r]) : 0.f;
          ls0[r] += p;
          const int prow = quad * 4 + r;
          pw0[prow * 64 + (((kg * 2 + (col >> 3)) ^ (prow & 7)) << 3) + (col & 7)] = f2bf(p);
        }
    }
    {
#pragma unroll
      for (int kg = 0; kg < 4; kg++)
#pragma unroll
        for (int r = 0; r < 4; r++) {
          int key = kt + kg * 16 + col, qg = qw1 + quad * 4 + r;
          float p = (key <= qg) ? __expf(s1[kg][r]) : 0.f;
          ls1[r] += p;
          const int prow = quad * 4 + r;
          pw1[prow * 64 + (((kg * 2 + (col >> 3)) ^ (prow & 7)) << 3) + (col & 7)] = f2bf(p);
        }
    }
    // merged PV: each vf read once, used by both q-subtiles
#pragma unroll
    for (int ks = 0; ks < 64; ks += 32) {
      const int cbase = ks >> 3;
      bf16x8 pf0, pf1;
      if (do0) pf0 = *(const bf16x8*)&pw0[col * 64 + (((cbase + quad) ^ (col & 7)) << 3)];
      pf1 = *(const bf16x8*)&pw1[col * 64 + (((cbase + quad) ^ (col & 7)) << 3)];
#pragma unroll
      for (int dt = 0; dt < 8; dt++) {
        const int vrow = dt * 16 + col;
        bf16x8 vf = *(const bf16x8*)&Vs[vrow * 64 + (((cbase + quad) ^ (vrow & 7)) << 3)];
        if (do0) o0[dt] = MFMA16(pf0, vf, o0[dt]);
        o1[dt] = MFMA16(pf1, vf, o1[dt]);
      }
    }
  }
  // single end-of-kernel row-sum reduction across the 16 cols
#pragma unroll
  for (int st = 1; st < 16; st <<= 1)
#pragma unroll
    for (int r = 0; r < 4; r++) {
      ls0[r] += __shfl_xor(ls0[r], st);
      ls1[r] += __shfl_xor(ls1[r], st);
    }
#pragma unroll
  for (int r = 0; r < 4; r++) {
    float inv0 = 1.0f / ls0[r], inv1 = 1.0f / ls1[r];
    size_t row0 = ((size_t)(b * 2048 + qw0 + quad * 4 + r)) * 2048 + h * 128;
    size_t row1 = ((size_t)(b * 2048 + qw1 + quad * 4 + r)) * 2048 + h * 128;
#pragma unroll
    for (int dt = 0; dt < 8; dt++) {
      O[row0 + dt * 16 + col] = f2bf(o0[dt][r] * inv0);
      O[row1 + dt * 16 + col] = f2bf(o1[dt][r] * inv1);
    }
  }
}

// ---------------- launch ----------------
extern "C" void kernel_launch(void* const* d_in, const int* in_sizes, int n_in,
                              void* d_out, int out_size, void* d_ws, size_t ws_size,
                              hipStream_t stream) {
  const float* x        = (const float*)d_in[0];  // [2,2048,2048]
  const float* rope_cos = (const float*)d_in[1];  // [1,1,2048,128]
  const float* rope_sin = (const float*)d_in[2];
  const float* qkv_w    = (const float*)d_in[3];  // [6144,2048]
  const float* qkv_b    = (const float*)d_in[4];  // [6144]
  const float* out_w    = (const float*)d_in[5];  // [2048,2048]
  const float* out_b    = (const float*)d_in[6];  // [2048]
  float* out = (float*)d_out;
  u16* ws = (u16*)d_ws;
  u16* xb    = ws;                  //  8388608 elems  (x bf16)
  u16* wqkvb = xb + 8388608;        // 12582912 elems
  u16* woutb = wqkvb + 12582912;    //  4194304 elems
  u16* qkvb  = woutb + 4194304;     // 25165824 elems
  u16* qb    = qkvb + 25165824;     //  8388608 elems
  u16* kb    = qb + 8388608;        //  8388608 elems
  u16* vtb   = kb + 8388608;        //  8388608 elems
  u16* attnb = xb;                  // reuse: xb dead after QKV GEMM

  // one fused cast dispatch (was 3 — launch overhead ~10-15us each)
  cvt3_kernel<<<24576, 256, 0, stream>>>(x, qkv_w, out_w, xb, wqkvb, woutb,
                                         2097152, 3145728, 1048576);
  // qkv = x * qkv_w^T + qkv_b  -> bf16 [4096][6144]  (single dispatch, r8 config)
  gemm_bt256<<<dim3(24, 16), 512, 0, stream>>>(xb, wqkvb, qkv_b, qkvb, 4096, 6144, 2048, 1);
  // rope + reorder + v-transpose
  rope_kernel<<<dim3(32, 32), 256, 0, stream>>>(qkvb, rope_cos, rope_sin, qb, kb, vtb);
  // causal flash attention -> bf16 [B,T,D]
  attn_kernel<<<dim3(512, 1), 256, 0, stream>>>(qb, kb, vtb, attnb);
  // out = attn * out_w^T + out_b -> f32 d_out  (BM=128: 256 blocks, full chip)
  gemm_bt128<<<dim3(8, 32), 512, 0, stream>>>(attnb, woutb, out_b, out, 4096, 2048, 2048, 0);
}

// Round 12
// 424.415 us; speedup vs baseline: 1.1475x; 1.1475x over previous
//
#include <hip/hip_runtime.h>
#include <cstdint>
#include <cstddef>

typedef unsigned short u16;
using bf16x8 = __attribute__((ext_vector_type(8))) short;
using f32x4  = __attribute__((ext_vector_type(4))) float;

#define MFMA16(a, b, c) __builtin_amdgcn_mfma_f32_16x16x32_bf16((a), (b), (c), 0, 0, 0)

__device__ __forceinline__ u16 f2bf(float f) {
  union { float f; unsigned u; } x; x.f = f;
  unsigned r = x.u + 0x7fffu + ((x.u >> 16) & 1u);
  return (u16)(r >> 16);
}
__device__ __forceinline__ float bf2f(u16 h) {
  union { unsigned u; float f; } x; x.u = ((unsigned)h) << 16;
  return x.f;
}
__device__ __forceinline__ void gll16(const void* g, void* l) {
  __builtin_amdgcn_global_load_lds((const __attribute__((address_space(1))) void*)g,
                                   (__attribute__((address_space(3))) void*)l, 16, 0, 0);
}

union U8 { bf16x8 v; u16 u[8]; };

// ---------------- fused fp32 -> bf16 cast for all three tensors ----------------
__global__ __launch_bounds__(256) void cvt3_kernel(const float* __restrict__ a,
                                                   const float* __restrict__ b,
                                                   const float* __restrict__ c,
                                                   u16* __restrict__ oa,
                                                   u16* __restrict__ ob,
                                                   u16* __restrict__ oc,
                                                   int n1, int n2, int n3) {
  int i = blockIdx.x * blockDim.x + threadIdx.x;
  const float* src; u16* dst; int j;
  if (i < n1)            { src = a; dst = oa; j = i; }
  else if (i < n1 + n2)  { src = b; dst = ob; j = i - n1; }
  else if (i < n1 + n2 + n3) { src = c; dst = oc; j = i - n1 - n2; }
  else return;
  float4 v = ((const float4*)src)[j];
  ushort4 o;
  o.x = f2bf(v.x); o.y = f2bf(v.y); o.z = f2bf(v.z); o.w = f2bf(v.w);
  ((ushort4*)dst)[j] = o;
}

// ---------------- 256x256 NT GEMM — m201-style 8-phase schedule ----
__global__ __launch_bounds__(512, 2) void gemm_bt256(const u16* __restrict__ A,
                                                     const u16* __restrict__ Bw,
                                                     const float* __restrict__ bias,
                                                     void* __restrict__ Cout,
                                                     int M, int N, int K, int out_bf16) {
  __shared__ u16 As_[2][16384];
  __shared__ u16 Bs_[2][16384];
  const int tid = threadIdx.x;
  const int lane = tid & 63, wave = tid >> 6;
  const int col = lane & 15, quad = lane >> 4;
  const int wr = wave >> 2, wc = wave & 3;
  const int bm = blockIdx.y, bn = blockIdx.x;
  const u16* Ag = A + (size_t)bm * 256 * K;
  const u16* Bg = Bw + (size_t)bn * 256 * K;
  const int srow = tid >> 2;                       // 0..127
  const int sslot = tid & 3;
  const int ssw = (sslot ^ ((srow >> 1) & 3)) << 3;
  const size_t g0 = (size_t)srow * K + ssw;
  const size_t g1 = (size_t)(srow + 128) * K + ssw;
  const int swq = (quad ^ ((col >> 1) & 3)) << 3;
  const int aro = (wr * 128 + col) * 32 + swq;
  const int bro = (wc * 64 + col) * 32 + swq;
  u16* const As0 = &As_[0][0]; u16* const As1 = &As_[1][0];
  u16* const Bs0 = &Bs_[0][0]; u16* const Bs1 = &Bs_[1][0];
  f32x4 acc[8][4] = {};
  bf16x8 a[8], bq[2];
  const int NI = K >> 7;  // iterations of 2 K-tiles

#define STG_A(BUF, KS, KT) do { \
    gll16(Ag + g0 + (KT) + (KS) * 32, (void*)((BUF) + (KS) * 8192 + tid * 8)); \
    gll16(Ag + g1 + (KT) + (KS) * 32, (void*)((BUF) + (KS) * 8192 + 4096 + tid * 8)); } while (0)
#define STG_B(BUF, KS, KT) do { \
    gll16(Bg + g0 + (KT) + (KS) * 32, (void*)((BUF) + (KS) * 8192 + tid * 8)); \
    gll16(Bg + g1 + (KT) + (KS) * 32, (void*)((BUF) + (KS) * 8192 + 4096 + tid * 8)); } while (0)
#define RD_A(BUF, KS) do { _Pragma("unroll") \
    for (int m_ = 0; m_ < 8; m_++) \
      a[m_] = *(const bf16x8*)&(BUF)[(KS) * 8192 + aro + m_ * 512]; } while (0)
#define RD_B(BUF, KS, NH) do { _Pragma("unroll") \
    for (int n_ = 0; n_ < 2; n_++) \
      bq[n_] = *(const bf16x8*)&(BUF)[(KS) * 8192 + bro + ((NH) * 2 + n_) * 512]; } while (0)
#define MM(NH) do { _Pragma("unroll") \
    for (int m_ = 0; m_ < 8; m_++) { _Pragma("unroll") \
      for (int n_ = 0; n_ < 2; n_++) \
        acc[m_][(NH) * 2 + n_] = MFMA16(a[m_], bq[n_], acc[m_][(NH) * 2 + n_]); } } while (0)
#define PH(RDS, STGS, MMS, WT) do { \
    RDS; STGS; \
    __builtin_amdgcn_s_barrier(); \
    asm volatile("s_waitcnt lgkmcnt(0)" ::: "memory"); \
    __builtin_amdgcn_s_setprio(1); \
    MMS; \
    __builtin_amdgcn_s_setprio(0); \
    WT; \
    __builtin_amdgcn_s_barrier(); } while (0)
#define VM6 do { asm volatile("s_waitcnt vmcnt(6)" ::: "memory"); } while (0)
#define VM0 do { asm volatile("s_waitcnt vmcnt(0)" ::: "memory"); } while (0)
#define NOPW do { } while (0)

#define ITER(I, LAST) do { \
    const int kt1_ = ((2 * (I) + 1) << 6), kt2_ = kt1_ + 64, kt3_ = kt2_ + 64; \
    PH({ RD_A(As0, 0); RD_B(Bs0, 0, 0); }, { STG_B(Bs1, 1, kt1_); },                MM(0), NOPW); \
    PH({ RD_B(Bs0, 0, 1); },               { if (!(LAST)) STG_A(As0, 0, kt2_); },   MM(1), NOPW); \
    PH({ RD_A(As0, 1); RD_B(Bs0, 1, 1); }, { if (!(LAST)) STG_B(Bs0, 0, kt2_); },   MM(1), NOPW); \
    PH({ RD_B(Bs0, 1, 0); },               { if (!(LAST)) STG_A(As0, 1, kt2_); },   MM(0), \
       if (LAST) { VM0; } else { VM6; }); \
    PH({ RD_A(As1, 0); RD_B(Bs1, 0, 0); }, { if (!(LAST)) STG_B(Bs0, 1, kt2_); },   MM(0), NOPW); \
    PH({ RD_B(Bs1, 0, 1); },               { if (!(LAST)) STG_A(As1, 0, kt3_); },   MM(1), NOPW); \
    PH({ RD_A(As1, 1); RD_B(Bs1, 1, 1); }, { if (!(LAST)) STG_B(Bs1, 0, kt3_); },   MM(1), NOPW); \
    PH({ RD_B(Bs1, 1, 0); },               { if (!(LAST)) STG_A(As1, 1, kt3_); },   MM(0), \
       if (!(LAST)) { VM6; }); \
  } while (0)

  // prologue: tile0 all 4 halves + tile1 first 3 (14 gll); confirm tile0.
  STG_A(As0, 0, 0);  STG_B(Bs0, 0, 0);  STG_A(As0, 1, 0);  STG_B(Bs0, 1, 0);
  STG_A(As1, 0, 64); STG_B(Bs1, 0, 64); STG_A(As1, 1, 64);
  VM6;
  __builtin_amdgcn_s_barrier();

  for (int i = 0; i < NI - 1; ++i) ITER(i, false);
  ITER(NI - 1, true);

  // epilogue
#pragma unroll
  for (int i = 0; i < 8; i++) {
    const int row0 = bm * 256 + wr * 128 + i * 16 + quad * 4;
#pragma unroll
    for (int j = 0; j < 4; j++) {
      const int cn = bn * 256 + wc * 64 + j * 16 + col;
      const float bv = bias[cn];
#pragma unroll
      for (int r = 0; r < 4; r++) {
        float v = acc[i][j][r] + bv;
        size_t off = (size_t)(row0 + r) * N + cn;
        if (out_bf16) ((u16*)Cout)[off] = f2bf(v);
        else          ((float*)Cout)[off] = v;
      }
    }
  }
#undef STG_A
#undef STG_B
#undef RD_A
#undef RD_B
#undef MM
#undef PH
#undef VM6
#undef VM0
#undef NOPW
#undef ITER
}

// ---------------- 128x256 NT GEMM — 8-phase schedule, BM=128 ----------------
// Out-projection: grid (8,32) = 256 blocks = exactly 1/CU.
__global__ __launch_bounds__(512, 2) void gemm_bt128(const u16* __restrict__ A,
                                                     const u16* __restrict__ Bw,
                                                     const float* __restrict__ bias,
                                                     void* __restrict__ Cout,
                                                     int M, int N, int K, int out_bf16) {
  __shared__ u16 As_[2][8192];
  __shared__ u16 Bs_[2][16384];
  const int tid = threadIdx.x;
  const int lane = tid & 63, wave = tid >> 6;
  const int col = lane & 15, quad = lane >> 4;
  const int wr = wave >> 2, wc = wave & 3;
  const int bm = blockIdx.y, bn = blockIdx.x;
  const u16* Ag = A + (size_t)bm * 128 * K;
  const u16* Bg = Bw + (size_t)bn * 256 * K;
  const int srow = tid >> 2;                       // 0..127
  const int sslot = tid & 3;
  const int ssw = (sslot ^ ((srow >> 1) & 3)) << 3;
  const size_t g0 = (size_t)srow * K + ssw;
  const size_t g1 = (size_t)(srow + 128) * K + ssw;   // B only
  const int swq = (quad ^ ((col >> 1) & 3)) << 3;
  const int aro = (wr * 64 + col) * 32 + swq;          // per-wave M = 64
  const int bro = (wc * 64 + col) * 32 + swq;
  u16* const As0 = &As_[0][0]; u16* const As1 = &As_[1][0];
  u16* const Bs0 = &Bs_[0][0]; u16* const Bs1 = &Bs_[1][0];
  f32x4 acc[4][4] = {};
  bf16x8 a[4], bq[2];
  const int NI = K >> 7;  // iterations of 2 K-tiles

#define STG_A(BUF, KS, KT) do { \
    gll16(Ag + g0 + (KT) + (KS) * 32, (void*)((BUF) + (KS) * 4096 + tid * 8)); } while (0)
#define STG_B(BUF, KS, KT) do { \
    gll16(Bg + g0 + (KT) + (KS) * 32, (void*)((BUF) + (KS) * 8192 + tid * 8)); \
    gll16(Bg + g1 + (KT) + (KS) * 32, (void*)((BUF) + (KS) * 8192 + 4096 + tid * 8)); } while (0)
#define RD_A(BUF, KS) do { _Pragma("unroll") \
    for (int m_ = 0; m_ < 4; m_++) \
      a[m_] = *(const bf16x8*)&(BUF)[(KS) * 4096 + aro + m_ * 512]; } while (0)
#define RD_B(BUF, KS, NH) do { _Pragma("unroll") \
    for (int n_ = 0; n_ < 2; n_++) \
      bq[n_] = *(const bf16x8*)&(BUF)[(KS) * 8192 + bro + ((NH) * 2 + n_) * 512]; } while (0)
#define MM(NH) do { _Pragma("unroll") \
    for (int m_ = 0; m_ < 4; m_++) { _Pragma("unroll") \
      for (int n_ = 0; n_ < 2; n_++) \
        acc[m_][(NH) * 2 + n_] = MFMA16(a[m_], bq[n_], acc[m_][(NH) * 2 + n_]); } } while (0)
#define PH(RDS, STGS, MMS, WT) do { \
    RDS; STGS; \
    __builtin_amdgcn_s_barrier(); \
    asm volatile("s_waitcnt lgkmcnt(0)" ::: "memory"); \
    __builtin_amdgcn_s_setprio(1); \
    MMS; \
    __builtin_amdgcn_s_setprio(0); \
    WT; \
    __builtin_amdgcn_s_barrier(); } while (0)
#define VM4 do { asm volatile("s_waitcnt vmcnt(4)" ::: "memory"); } while (0)
#define VM0 do { asm volatile("s_waitcnt vmcnt(0)" ::: "memory"); } while (0)
#define NOPW do { } while (0)

#define ITER(I, LAST) do { \
    const int kt1_ = ((2 * (I) + 1) << 6), kt2_ = kt1_ + 64, kt3_ = kt2_ + 64; \
    PH({ RD_A(As0, 0); RD_B(Bs0, 0, 0); }, { STG_B(Bs1, 1, kt1_); },                MM(0), NOPW); \
    PH({ RD_B(Bs0, 0, 1); },               { if (!(LAST)) STG_A(As0, 0, kt2_); },   MM(1), NOPW); \
    PH({ RD_A(As0, 1); RD_B(Bs0, 1, 1); }, { if (!(LAST)) STG_B(Bs0, 0, kt2_); },   MM(1), NOPW); \
    PH({ RD_B(Bs0, 1, 0); },               { if (!(LAST)) STG_A(As0, 1, kt2_); },   MM(0), \
       if (LAST) { VM0; } else { VM4; }); \
    PH({ RD_A(As1, 0); RD_B(Bs1, 0, 0); }, { if (!(LAST)) STG_B(Bs0, 1, kt2_); },   MM(0), NOPW); \
    PH({ RD_B(Bs1, 0, 1); },               { if (!(LAST)) STG_A(As1, 0, kt3_); },   MM(1), NOPW); \
    PH({ RD_A(As1, 1); RD_B(Bs1, 1, 1); }, { if (!(LAST)) STG_B(Bs1, 0, kt3_); },   MM(1), NOPW); \
    PH({ RD_B(Bs1, 1, 0); },               { if (!(LAST)) STG_A(As1, 1, kt3_); },   MM(0), \
       if (!(LAST)) { VM4; }); \
  } while (0)

  // prologue: tile0 all 4 halves (6 gll) + tile1 A0,B0,A1 (4 gll); confirm tile0.
  STG_A(As0, 0, 0);  STG_B(Bs0, 0, 0);  STG_A(As0, 1, 0);  STG_B(Bs0, 1, 0);
  STG_A(As1, 0, 64); STG_B(Bs1, 0, 64); STG_A(As1, 1, 64);
  VM4;
  __builtin_amdgcn_s_barrier();

  for (int i = 0; i < NI - 1; ++i) ITER(i, false);
  ITER(NI - 1, true);

  // epilogue
#pragma unroll
  for (int i = 0; i < 4; i++) {
    const int row0 = bm * 128 + wr * 64 + i * 16 + quad * 4;
#pragma unroll
    for (int j = 0; j < 4; j++) {
      const int cn = bn * 256 + wc * 64 + j * 16 + col;
      const float bv = bias[cn];
#pragma unroll
      for (int r = 0; r < 4; r++) {
        float v = acc[i][j][r] + bv;
        size_t off = (size_t)(row0 + r) * N + cn;
        if (out_bf16) ((u16*)Cout)[off] = f2bf(v);
        else          ((float*)Cout)[off] = v;
      }
    }
  }
#undef STG_A
#undef STG_B
#undef RD_A
#undef RD_B
#undef MM
#undef PH
#undef VM4
#undef VM0
#undef NOPW
#undef ITER
}

// ---------------- RoPE + reorder + V transpose ----------------
__global__ __launch_bounds__(256) void rope_kernel(const u16* __restrict__ qkv,
                                                   const float* __restrict__ cosT,
                                                   const float* __restrict__ sinT,
                                                   u16* __restrict__ qo,
                                                   u16* __restrict__ ko,
                                                   u16* __restrict__ vt) {
  __shared__ u16 vs[128 * 72];
  const int bh = blockIdx.x;
  const int b = bh >> 4, h = bh & 15;
  const int tb = blockIdx.y;
  const int tid = threadIdx.x;
  const int tl = tid >> 2;        // 0..63
  const int g = tid & 3;
  const int t = tb * 64 + tl;
  const size_t qrow = ((size_t)(b * 2048 + t)) * 6144 + h * 128;
  const size_t orow = ((size_t)bh * 2048 + t) * 128;
  const int tt = t * 128;
  const int dl = g * 16, dh = 64 + dl;
  const float scale = 0.08838834764831845f;  // 1/sqrt(128)
#pragma unroll
  for (int cch = 0; cch < 2; cch++) {
    const int o8 = cch * 8;
    U8 ql, qh, kl, kh, vl, vh;
    ql.v = *(const bf16x8*)&qkv[qrow + dl + o8];
    qh.v = *(const bf16x8*)&qkv[qrow + dh + o8];
    kl.v = *(const bf16x8*)&qkv[qrow + 2048 + dl + o8];
    kh.v = *(const bf16x8*)&qkv[qrow + 2048 + dh + o8];
    vl.v = *(const bf16x8*)&qkv[qrow + 4096 + dl + o8];
    vh.v = *(const bf16x8*)&qkv[qrow + 4096 + dh + o8];
    float cl[8], ch_[8], sl[8], sh_[8];
    *(float4*)&cl[0]  = *(const float4*)&cosT[tt + dl + o8];
    *(float4*)&cl[4]  = *(const float4*)&cosT[tt + dl + o8 + 4];
    *(float4*)&ch_[0] = *(const float4*)&cosT[tt + dh + o8];
    *(float4*)&ch_[4] = *(const float4*)&cosT[tt + dh + o8 + 4];
    *(float4*)&sl[0]  = *(const float4*)&sinT[tt + dl + o8];
    *(float4*)&sl[4]  = *(const float4*)&sinT[tt + dl + o8 + 4];
    *(float4*)&sh_[0] = *(const float4*)&sinT[tt + dh + o8];
    *(float4*)&sh_[4] = *(const float4*)&sinT[tt + dh + o8 + 4];
    U8 aq, bq, ak, bk;
#pragma unroll
    for (int i = 0; i < 8; i++) {
      float qlf = bf2f(ql.u[i]), qhf = bf2f(qh.u[i]);
      float klf = bf2f(kl.u[i]), khf = bf2f(kh.u[i]);
      aq.u[i] = f2bf((qlf * cl[i]  - qhf * sl[i])  * scale);
      bq.u[i] = f2bf((qhf * ch_[i] + qlf * sh_[i]) * scale);
      ak.u[i] = f2bf(klf * cl[i]  - khf * sl[i]);
      bk.u[i] = f2bf(khf * ch_[i] + klf * sh_[i]);
    }
    *(bf16x8*)&qo[orow + dl + o8] = aq.v;
    *(bf16x8*)&qo[orow + dh + o8] = bq.v;
    *(bf16x8*)&ko[orow + dl + o8] = ak.v;
    *(bf16x8*)&ko[orow + dh + o8] = bk.v;
#pragma unroll
    for (int i = 0; i < 8; i++) {
      vs[(dl + o8 + i) * 72 + tl] = vl.u[i];
      vs[(dh + o8 + i) * 72 + tl] = vh.u[i];
    }
  }
  __syncthreads();
#pragma unroll
  for (int c = 0; c < 4; c++) {
    int idx = c * 256 + tid;
    int dd = idx >> 3, chk = idx & 7;
    bf16x8 vv = *(const bf16x8*)&vs[dd * 72 + chk * 8];
    *(bf16x8*)&vt[((size_t)bh * 128 + dd) * 2048 + tb * 64 + chk * 8] = vv;
  }
}

// ---------------- causal flash attention (no-max softmax) ----------------
// r10-verified optimum (92.3us): r0-3 compute structure + padded LDS +
// complementarity-paired balance map (r7). VGPR = exactly 128 — do NOT
// add register pressure here: r11's merged-PV pushed 148 VGPR, crossed the
// 128-reg occupancy boundary (waves/SIMD halve at 64/128/256), and
// regressed to 156us despite fewer bank conflicts.
__global__ __launch_bounds__(256) void attn_kernel(const u16* __restrict__ Q,
                                                   const u16* __restrict__ Kk,
                                                   const u16* __restrict__ Vt,
                                                   u16* __restrict__ O) {
  __shared__ u16 Ks[64 * 136];       // 64 keys x 128 dims (+pad)
  __shared__ u16 Vs[128 * 72];       // 128 dims x 64 keys (+pad)
  __shared__ u16 Ps[4][16 * 72];     // per-wave P scratch: 16 q x 64 keys (+pad)
  const int L = blockIdx.x;          // 0..511
  const int bh = (L < 256) ? (L >> 4) : 16 + ((L - 256) >> 4);
  const int qtile = (L < 256) ? (15 - (L & 15)) : (L & 15);
  const int b = bh >> 4, h = bh & 15;
  const int qb = qtile * 128;
  const int tid = threadIdx.x, wave = tid >> 6, lane = tid & 63;
  const int col = lane & 15, quad = lane >> 4;
  const int qw0 = qb + wave * 32;    // wave owns rows [qw0, qw0+31]
  const int qw1 = qw0 + 16;
  const u16* Qg = Q + (size_t)bh * 2048 * 128;
  const u16* Kg = Kk + (size_t)bh * 2048 * 128;
  const u16* Vg = Vt + (size_t)bh * 128 * 2048;
  bf16x8 qf0[4], qf1[4];
#pragma unroll
  for (int c = 0; c < 4; c++) {
    qf0[c] = *(const bf16x8*)&Qg[(size_t)(qw0 + col) * 128 + c * 32 + quad * 8];
    qf1[c] = *(const bf16x8*)&Qg[(size_t)(qw1 + col) * 128 + c * 32 + quad * 8];
  }
  f32x4 o0[8] = {}, o1[8] = {};
  float ls0[4] = {0.f, 0.f, 0.f, 0.f}, ls1[4] = {0.f, 0.f, 0.f, 0.f};
  const int ntiles = (qb + 128) >> 6;
  const int kr = tid >> 2, kc = (tid & 3) * 8;  // K staging: 4 thr/row
  const int vr = tid >> 1, vc = (tid & 1) * 8;  // V staging: 2 thr/row
  for (int it = 0; it < ntiles; ++it) {
    const int kt = it << 6;
    __syncthreads();
#pragma unroll
    for (int u = 0; u < 4; u++)
      *(bf16x8*)&Ks[kr * 136 + kc + u * 32] =
          *(const bf16x8*)&Kg[(size_t)(kt + kr) * 128 + kc + u * 32];
#pragma unroll
    for (int u = 0; u < 4; u++)
      *(bf16x8*)&Vs[vr * 72 + vc + u * 16] =
          *(const bf16x8*)&Vg[(size_t)vr * 2048 + kt + vc + u * 16];
    __syncthreads();
    if (kt > qw1 + 15) continue;     // wave-uniform; barriers stay matched
    const bool do0 = (kt <= qw0 + 15);
    f32x4 s0[4] = {}, s1[4] = {};
#pragma unroll
    for (int c = 0; c < 4; c++) {
#pragma unroll
      for (int kg = 0; kg < 4; kg++) {
        bf16x8 kf = *(const bf16x8*)&Ks[(kg * 16 + col) * 136 + c * 32 + quad * 8];
        s0[kg] = MFMA16(qf0[c], kf, s0[kg]);
        s1[kg] = MFMA16(qf1[c], kf, s1[kg]);
      }
    }
    u16* pw = Ps[wave];
    if (do0) {  // q-tile 0: exp+mask, P->LDS->A-frag, PV
#pragma unroll
      for (int kg = 0; kg < 4; kg++)
#pragma unroll
        for (int r = 0; r < 4; r++) {
          int key = kt + kg * 16 + col, qg = qw0 + quad * 4 + r;
          float p = (key <= qg) ? __expf(s0[kg][r]) : 0.f;
          ls0[r] += p;
          pw[(quad * 4 + r) * 72 + kg * 16 + col] = f2bf(p);
        }
#pragma unroll
      for (int ks = 0; ks < 64; ks += 32) {
        bf16x8 pf = *(const bf16x8*)&pw[col * 72 + ks + quad * 8];
#pragma unroll
        for (int dt = 0; dt < 8; dt++) {
          bf16x8 vf = *(const bf16x8*)&Vs[(dt * 16 + col) * 72 + ks + quad * 8];
          o0[dt] = MFMA16(pf, vf, o0[dt]);
        }
      }
    }
    {  // q-tile 1
#pragma unroll
      for (int kg = 0; kg < 4; kg++)
#pragma unroll
        for (int r = 0; r < 4; r++) {
          int key = kt + kg * 16 + col, qg = qw1 + quad * 4 + r;
          float p = (key <= qg) ? __expf(s1[kg][r]) : 0.f;
          ls1[r] += p;
          pw[(quad * 4 + r) * 72 + kg * 16 + col] = f2bf(p);
        }
#pragma unroll
      for (int ks = 0; ks < 64; ks += 32) {
        bf16x8 pf = *(const bf16x8*)&pw[col * 72 + ks + quad * 8];
#pragma unroll
        for (int dt = 0; dt < 8; dt++) {
          bf16x8 vf = *(const bf16x8*)&Vs[(dt * 16 + col) * 72 + ks + quad * 8];
          o1[dt] = MFMA16(pf, vf, o1[dt]);
        }
      }
    }
  }
  // single end-of-kernel row-sum reduction across the 16 cols
#pragma unroll
  for (int st = 1; st < 16; st <<= 1)
#pragma unroll
    for (int r = 0; r < 4; r++) {
      ls0[r] += __shfl_xor(ls0[r], st);
      ls1[r] += __shfl_xor(ls1[r], st);
    }
#pragma unroll
  for (int r = 0; r < 4; r++) {
    float inv0 = 1.0f / ls0[r], inv1 = 1.0f / ls1[r];
    size_t row0 = ((size_t)(b * 2048 + qw0 + quad * 4 + r)) * 2048 + h * 128;
    size_t row1 = ((size_t)(b * 2048 + qw1 + quad * 4 + r)) * 2048 + h * 128;
#pragma unroll
    for (int dt = 0; dt < 8; dt++) {
      O[row0 + dt * 16 + col] = f2bf(o0[dt][r] * inv0);
      O[row1 + dt * 16 + col] = f2bf(o1[dt][r] * inv1);
    }
  }
}

// ---------------- launch ----------------
extern "C" void kernel_launch(void* const* d_in, const int* in_sizes, int n_in,
                              void* d_out, int out_size, void* d_ws, size_t ws_size,
                              hipStream_t stream) {
  const float* x        = (const float*)d_in[0];  // [2,2048,2048]
  const float* rope_cos = (const float*)d_in[1];  // [1,1,2048,128]
  const float* rope_sin = (const float*)d_in[2];
  const float* qkv_w    = (const float*)d_in[3];  // [6144,2048]
  const float* qkv_b    = (const float*)d_in[4];  // [6144]
  const float* out_w    = (const float*)d_in[5];  // [2048,2048]
  const float* out_b    = (const float*)d_in[6];  // [2048]
  float* out = (float*)d_out;
  u16* ws = (u16*)d_ws;
  u16* xb    = ws;                  //  8388608 elems  (x bf16)
  u16* wqkvb = xb + 8388608;        // 12582912 elems
  u16* woutb = wqkvb + 12582912;    //  4194304 elems
  u16* qkvb  = woutb + 4194304;     // 25165824 elems
  u16* qb    = qkvb + 25165824;     //  8388608 elems
  u16* kb    = qb + 8388608;        //  8388608 elems
  u16* vtb   = kb + 8388608;        //  8388608 elems
  u16* attnb = xb;                  // reuse: xb dead after QKV GEMM

  // one fused cast dispatch (was 3 — launch overhead each)
  cvt3_kernel<<<24576, 256, 0, stream>>>(x, qkv_w, out_w, xb, wqkvb, woutb,
                                         2097152, 3145728, 1048576);
  // qkv = x * qkv_w^T + qkv_b  -> bf16 [4096][6144]
  gemm_bt256<<<dim3(24, 16), 512, 0, stream>>>(xb, wqkvb, qkv_b, qkvb, 4096, 6144, 2048, 1);
  // rope + reorder + v-transpose
  rope_kernel<<<dim3(32, 32), 256, 0, stream>>>(qkvb, rope_cos, rope_sin, qb, kb, vtb);
  // causal flash attention -> bf16 [B,T,D]
  attn_kernel<<<dim3(512, 1), 256, 0, stream>>>(qb, kb, vtb, attnb);
  // out = attn * out_w^T + out_b -> f32 d_out  (BM=128: 256 blocks, full chip)
  gemm_bt128<<<dim3(8, 32), 512, 0, stream>>>(attnb, woutb, out_b, out, 4096, 2048, 2048, 0);
}